// Round 1
// baseline (229.746 us; speedup 1.0000x reference)
//
#include <hip/hip_runtime.h>

#define DEVFN __device__ __forceinline__

// NaN-propagating relu (fmaxf(NaN,0)==0 would mask upstream failures).
DEVFN float relu(float x) { return x < 0.f ? 0.f : x; }

// ---------------------------------------------------------------------------
// KA: fused pre-work, two block roles interleaved (bx%3): 2/3 src, 1/3 nbr.
//  src role : src = features@in_w+in_b + relu(pe)@pe_w2+pe_b2 ; qs/ks/vs
//  nbr role : neighbor top-16 (manhattan<=4, stable); nbr-block 0 zeros BN.
// __launch_bounds__(256,4): grid gives 4-6 blocks/CU; allow 128 VGPRs.
// GEMM loops use 1-deep register software-pipelining of the weight streams:
// VGPR was 60 (compiler chose minimal depth) -> L2 latency (~200-300cy) on the
// strided weight loads was exposed every iteration at only 4 waves/SIMD.
// ---------------------------------------------------------------------------
__global__ __launch_bounds__(256, 4) void ka_pre_cst(
    const float* __restrict__ features, const int* __restrict__ coords,
    const float* __restrict__ pe_w1, const float* __restrict__ pe_b1,
    const float* __restrict__ pe_w2, const float* __restrict__ pe_b2,
    const float* __restrict__ in_w, const float* __restrict__ in_b,
    const float* __restrict__ q_w, const float* __restrict__ k_w,
    const float* __restrict__ v_w,
    float* __restrict__ src,
    float* __restrict__ qs, float* __restrict__ ks, float* __restrict__ vs,
    int* __restrict__ nbr, float* __restrict__ bnAcc, int N)
{
    // src-role LDS
    __shared__ __align__(16) float sF[512];   // 8 rows x 64 features
    __shared__ __align__(16) float sH[512];   // 8 rows x 64 pe-hidden
    __shared__ __align__(16) float S[1024];   // 8 rows x 128 src
    __shared__ int   sC[24];
    // nbr-role LDS
    __shared__ int cnt[16];
    __shared__ int lst[16 * 64];
    __shared__ int outL[256];

    const int tid = threadIdx.x;
    const int bx = blockIdx.x;
    const int role_nbr = (bx % 3) == 2;

    if (role_nbr) {
        // ---------------- nbr role: neighbor search -----------------------
        const int nb = bx / 3;
        const int q0 = nb * 16;
        if (nb == 0 && tid < 128) bnAcc[tid] = 0.f;
        if (tid < 16) cnt[tid] = 0;
        outL[tid] = -1;
        __syncthreads();
        int qx[16], qy[16], qz[16];
#pragma unroll
        for (int q = 0; q < 16; ++q) {
            qx[q] = coords[(q0 + q) * 3 + 0];
            qy[q] = coords[(q0 + q) * 3 + 1];
            qz[q] = coords[(q0 + q) * 3 + 2];
        }
        for (int cd = tid; cd < N; cd += 256) {
            int cx = coords[cd * 3 + 0];
            int cy = coords[cd * 3 + 1];
            int cz = coords[cd * 3 + 2];
#pragma unroll
            for (int q = 0; q < 16; ++q) {
                int dx = cx - qx[q]; dx = dx < 0 ? -dx : dx;
                int dy = cy - qy[q]; dy = dy < 0 ? -dy : dy;
                int dz = cz - qz[q]; dz = dz < 0 ? -dz : dz;
                int d = dx + dy + dz;
                if (d <= 4) {
                    int s = atomicAdd(&cnt[q], 1);
                    if (s < 64) lst[q * 64 + s] = (d << 13) | cd;
                }
            }
        }
        __syncthreads();
        {
            const int q = tid >> 4, t = tid & 15;
            int n = cnt[q]; if (n > 64) n = 64;
            for (int e = t; e < n; e += 16) {
                int key = lst[q * 64 + e];
                int rank = 0;
                for (int j = 0; j < n; ++j) rank += (lst[q * 64 + j] < key) ? 1 : 0;
                if (rank < 16) outL[q * 16 + rank] = key & 8191;
            }
        }
        __syncthreads();
        {
            const int q = tid >> 4, t = tid & 15;
            nbr[(q0 + q) * 16 + t] = outL[q * 16 + t];
        }
        return;
    }

    // ---------------- src role: src + q/k/v projections -------------------
    const int sb = (bx / 3) * 2 + (bx % 3);   // 0..1023
    const int r0 = sb * 8;
    if (tid < 24) sC[tid] = coords[r0 * 3 + tid];
    for (int i = tid; i < 512; i += 256) sF[i] = features[r0 * 64 + i];
    __syncthreads();
    for (int i = tid; i < 512; i += 256) {
        int r = i >> 6, t = i & 63;
        float v0 = sC[r * 3 + 0] * (1.f / 95.f);
        float v1 = sC[r * 3 + 1] * (1.f / 95.f);
        float v2 = sC[r * 3 + 2] * (1.f / 95.f);
        float h = v0 * pe_w1[t] + v1 * pe_w1[64 + t] + v2 * pe_w1[128 + t] + pe_b1[t];
        sH[i] = relu(h);
    }
    __syncthreads();
    const int c = tid & 127, rh = tid >> 7;
    {
        // src = sF @ in_w + sH @ pe_w2 + (in_b + pe_b2), float4-granular with
        // 1-deep weight prefetch (wrap via &15 keeps the lookahead in-bounds).
        float acc[4];
        const float base = in_b[c] + pe_b2[c];
#pragma unroll
        for (int r = 0; r < 4; ++r) acc[r] = base;
        const float* wi = in_w + c;
        const float* wp = pe_w2 + c;
        float i0 = wi[0 * 128], i1 = wi[1 * 128], i2 = wi[2 * 128], i3 = wi[3 * 128];
        float p0 = wp[0 * 128], p1 = wp[1 * 128], p2 = wp[2 * 128], p3 = wp[3 * 128];
        for (int j4 = 0; j4 < 16; ++j4) {
            const int jn = ((j4 + 1) & 15) * 4;
            float ni0 = wi[(jn + 0) * 128], ni1 = wi[(jn + 1) * 128];
            float ni2 = wi[(jn + 2) * 128], ni3 = wi[(jn + 3) * 128];
            float np0 = wp[(jn + 0) * 128], np1 = wp[(jn + 1) * 128];
            float np2 = wp[(jn + 2) * 128], np3 = wp[(jn + 3) * 128];
#pragma unroll
            for (int r = 0; r < 4; ++r) {
                const int rr = rh * 4 + r;
                float4 f = *(const float4*)(&sF[rr * 64 + j4 * 4]);
                float4 h = *(const float4*)(&sH[rr * 64 + j4 * 4]);
                acc[r] += f.x * i0 + f.y * i1 + f.z * i2 + f.w * i3
                        + h.x * p0 + h.y * p1 + h.z * p2 + h.w * p3;
            }
            i0 = ni0; i1 = ni1; i2 = ni2; i3 = ni3;
            p0 = np0; p1 = np1; p2 = np2; p3 = np3;
        }
#pragma unroll
        for (int r = 0; r < 4; ++r) {
            src[(r0 + rh * 4 + r) * 128 + c] = acc[r];
            S[(rh * 4 + r) * 128 + c] = acc[r];
        }
    }
    __syncthreads();
    // q/k/v in one pass: 12 concurrent weight streams + 1-deep prefetch.
    {
        float aq[4], ak[4], av[4];
#pragma unroll
        for (int r = 0; r < 4; ++r) { aq[r] = 0.f; ak[r] = 0.f; av[r] = 0.f; }
        const float* wq = q_w + c;
        const float* wk = k_w + c;
        const float* wv = v_w + c;
        float q0 = wq[0 * 128], q1 = wq[1 * 128], q2 = wq[2 * 128], q3 = wq[3 * 128];
        float k0 = wk[0 * 128], k1 = wk[1 * 128], k2 = wk[2 * 128], k3 = wk[3 * 128];
        float v0 = wv[0 * 128], v1 = wv[1 * 128], v2 = wv[2 * 128], v3 = wv[3 * 128];
        for (int k4 = 0; k4 < 32; ++k4) {
            const int kn = ((k4 + 1) & 31) * 4;
            float nq0 = wq[(kn + 0) * 128], nq1 = wq[(kn + 1) * 128];
            float nq2 = wq[(kn + 2) * 128], nq3 = wq[(kn + 3) * 128];
            float nk0 = wk[(kn + 0) * 128], nk1 = wk[(kn + 1) * 128];
            float nk2 = wk[(kn + 2) * 128], nk3 = wk[(kn + 3) * 128];
            float nv0 = wv[(kn + 0) * 128], nv1 = wv[(kn + 1) * 128];
            float nv2 = wv[(kn + 2) * 128], nv3 = wv[(kn + 3) * 128];
#pragma unroll
            for (int r = 0; r < 4; ++r) {
                float4 s = *(const float4*)(&S[(rh * 4 + r) * 128 + k4 * 4]);
                aq[r] += s.x * q0 + s.y * q1 + s.z * q2 + s.w * q3;
                ak[r] += s.x * k0 + s.y * k1 + s.z * k2 + s.w * k3;
                av[r] += s.x * v0 + s.y * v1 + s.z * v2 + s.w * v3;
            }
            q0 = nq0; q1 = nq1; q2 = nq2; q3 = nq3;
            k0 = nk0; k1 = nk1; k2 = nk2; k3 = nk3;
            v0 = nv0; v1 = nv1; v2 = nv2; v3 = nv3;
        }
#pragma unroll
        for (int r = 0; r < 4; ++r) {
            qs[(r0 + rh * 4 + r) * 128 + c] = aq[r];
            ks[(r0 + rh * 4 + r) * 128 + c] = ak[r];
            vs[(r0 + rh * 4 + r) * 128 + c] = av[r];
        }
    }
}

// ---------------------------------------------------------------------------
// K4: attention + o-proj + LN1 + FFN + LN2 + fusion + BN partials.
// 8 rows/block, 1024 blocks (4/CU). GEMM phases 2/4 use K-split mapping:
// thread = (col, K-half), 8-row accumulators, LDS reduction — halves the
// per-thread weight-load instruction count vs (col, row-half).
// All GEMM loops software-pipeline the weight stream 1 iteration deep.
// ---------------------------------------------------------------------------
DEVFN void ln_rows8(float* Cb, const float* __restrict__ g,
                    const float* __restrict__ b, int tid)
{
    const int r = tid >> 5, l = tid & 31;
    float x[4]; float s = 0.f, s2 = 0.f;
#pragma unroll
    for (int i = 0; i < 4; ++i) {
        x[i] = Cb[r * 128 + l * 4 + i];
        s += x[i]; s2 += x[i] * x[i];
    }
#pragma unroll
    for (int o = 1; o < 32; o <<= 1) { s += __shfl_xor(s, o); s2 += __shfl_xor(s2, o); }
    float mu = s * (1.f / 128.f);
    float var = s2 * (1.f / 128.f) - mu * mu;
    float rstd = rsqrtf(var + 1e-5f);
#pragma unroll
    for (int i = 0; i < 4; ++i) {
        int cc = l * 4 + i;
        Cb[r * 128 + cc] = (x[i] - mu) * rstd * g[cc] + b[cc];
    }
}

__global__ __launch_bounds__(256, 4) void k4_main_cst(
    const float* __restrict__ features, const float* __restrict__ src,
    const float* __restrict__ qs, const float* __restrict__ ks, const float* __restrict__ vs,
    const int* __restrict__ nbr,
    const float* __restrict__ q_b, const float* __restrict__ k_b,
    const float* __restrict__ v_b,
    const float* __restrict__ o_w, const float* __restrict__ o_b,
    const float* __restrict__ n1_g, const float* __restrict__ n1_b,
    const float* __restrict__ l1_w, const float* __restrict__ l1_b,
    const float* __restrict__ l2_w, const float* __restrict__ l2_b,
    const float* __restrict__ n3_g, const float* __restrict__ n3_b,
    const float* __restrict__ fu_w, const float* __restrict__ fu_b,
    float* __restrict__ fused, float* __restrict__ bnSum, float* __restrict__ bnSq)
{
    __shared__ __align__(16) float A[1024];           // src tile / phase-4 partial kh=0
    __shared__ __align__(16) float Bt[1024];          // head_out / phase-4 partial kh=1
    __shared__ __align__(16) float C[1024];           // running activation
    __shared__ __align__(16) float Q[1024];           // q rows (bias applied)
    __shared__ __align__(16) float H[2048];           // phase-2 partials / ffn hidden / bn staging
    __shared__ __align__(16) float SC[512];           // attention scores
    __shared__ __align__(16) float F[512];            // features tile
    __shared__ __align__(16) float bK[128], bV[128];
    __shared__ int idxL[128];
    const int tid = threadIdx.x;
    const int r0 = blockIdx.x * 8;

    for (int i = tid; i < 1024; i += 256) A[i] = src[r0 * 128 + i];
    for (int i = tid; i < 512; i += 256) F[i] = features[r0 * 64 + i];
    if (tid < 128) {
        idxL[tid] = nbr[r0 * 16 + tid];
        bK[tid] = k_b[tid]; bV[tid] = v_b[tid];
    }
    __syncthreads();
    {   // vectorized Q gather + bias: thread = (row=tid>>5, colgroup=tid&31)
        int r = tid >> 5, cg = tid & 31;
        int i0 = idxL[r * 16];
        float4 qv = make_float4(0.f, 0.f, 0.f, 0.f);
        if (i0 >= 0) qv = *(const float4*)(qs + i0 * 128 + cg * 4);
        float4 qb = *(const float4*)(q_b + cg * 4);
        qv.x += qb.x; qv.y += qb.y; qv.z += qb.z; qv.w += qb.w;
        *(float4*)(&Q[r * 128 + cg * 4]) = qv;
    }
    __syncthreads();

    // ---- phase 1a: scores. thread = (row r, head h, group g of 8) --------
    const int ar = tid >> 5, ah = (tid >> 3) & 3, ag = tid & 7;
    {
#pragma unroll
        for (int jj = 0; jj < 2; ++jj) {
            int j = ag + jj * 8;
            int j4 = j >> 2, ch = j & 3;
            int id = idxL[ar * 16 + ah * 4 + j4];
            float s = 0.f;
#pragma unroll
            for (int c4 = 0; c4 < 8; ++c4) {
                float4 qv = *(const float4*)(&Q[ar * 128 + ah * 32 + c4 * 4]);
                float4 kb = *(const float4*)(&bK[ch * 32 + c4 * 4]);
                float4 kv = make_float4(0.f, 0.f, 0.f, 0.f);
                if (id >= 0) kv = *(const float4*)(ks + id * 128 + ch * 32 + c4 * 4);
                s += qv.x * (kv.x + kb.x) + qv.y * (kv.y + kb.y)
                   + qv.z * (kv.z + kb.z) + qv.w * (kv.w + kb.w);
            }
            SC[ar * 64 + ah * 16 + j] = s * 0.08838834764831845f;  // 1/sqrt(128)
        }
    }
    __syncthreads();

    // ---- phase 1b: softmax (redundant per 8-thread group) + P@V ----------
    {
        float p[16];
        float mx = -3.4e38f;
#pragma unroll
        for (int j = 0; j < 16; ++j) { p[j] = SC[ar * 64 + ah * 16 + j]; mx = fmaxf(mx, p[j]); }
        float sum = 0.f;
#pragma unroll
        for (int j = 0; j < 16; ++j) { p[j] = __expf(p[j] - mx); sum += p[j]; }
        float inv = 1.f / sum;
        float4 acc = make_float4(0.f, 0.f, 0.f, 0.f);
#pragma unroll
        for (int j = 0; j < 16; ++j) {
            int j4 = j >> 2, ch = j & 3;
            int id = idxL[ar * 16 + ah * 4 + j4];
            float4 vb = *(const float4*)(&bV[ch * 32 + ag * 4]);
            float4 vv = make_float4(0.f, 0.f, 0.f, 0.f);
            if (id >= 0) vv = *(const float4*)(vs + id * 128 + ch * 32 + ag * 4);
            float w = p[j] * inv;
            acc.x += w * (vv.x + vb.x); acc.y += w * (vv.y + vb.y);
            acc.z += w * (vv.z + vb.z); acc.w += w * (vv.w + vb.w);
        }
        *(float4*)(&Bt[ar * 128 + ah * 32 + ag * 4]) = acc;
    }
    __syncthreads();

    // ---- phase 2: out = head_out @ o_w (K-split); C = A + out + o_b ------
    {
        const int c = tid & 127, kh = tid >> 7;
        float acc[8];
#pragma unroll
        for (int r = 0; r < 8; ++r) acc[r] = 0.f;
        const float* wp = o_w + kh * 64 * 128 + c;
        float w0 = wp[0 * 128], w1 = wp[1 * 128], w2 = wp[2 * 128], w3 = wp[3 * 128];
        for (int k4 = 0; k4 < 16; ++k4) {
            const int kn = ((k4 + 1) & 15) * 4;
            float n0 = wp[(kn + 0) * 128], n1 = wp[(kn + 1) * 128];
            float n2 = wp[(kn + 2) * 128], n3 = wp[(kn + 3) * 128];
#pragma unroll
            for (int r = 0; r < 8; ++r) {
                float4 t = *(const float4*)(&Bt[r * 128 + kh * 64 + k4 * 4]);
                acc[r] += t.x * w0 + t.y * w1 + t.z * w2 + t.w * w3;
            }
            w0 = n0; w1 = n1; w2 = n2; w3 = n3;
        }
#pragma unroll
        for (int r = 0; r < 8; ++r) H[kh * 1024 + r * 128 + c] = acc[r];
    }
    __syncthreads();
    for (int i = tid; i < 1024; i += 256) {
        int c = i & 127;
        C[i] = A[i] + o_b[c] + H[i] + H[1024 + i];
    }
    __syncthreads();
    ln_rows8(C, n1_g, n1_b, tid);   // C = tgt
    __syncthreads();

    // ---- phase 3: H = relu(C @ l1_w + l1_b)  [8 x 256] -------------------
    {
        const int f = tid;
        float acc[8];
#pragma unroll
        for (int r = 0; r < 8; ++r) acc[r] = 0.f;
        const float* wp = l1_w + f;
        float w0 = wp[0 * 256], w1 = wp[1 * 256], w2 = wp[2 * 256], w3 = wp[3 * 256];
        for (int k4 = 0; k4 < 32; ++k4) {
            const int kn = ((k4 + 1) & 31) * 4;
            float n0 = wp[(kn + 0) * 256], n1 = wp[(kn + 1) * 256];
            float n2 = wp[(kn + 2) * 256], n3 = wp[(kn + 3) * 256];
#pragma unroll
            for (int r = 0; r < 8; ++r) {
                float4 t = *(const float4*)(&C[r * 128 + k4 * 4]);
                acc[r] += t.x * w0 + t.y * w1 + t.z * w2 + t.w * w3;
            }
            w0 = n0; w1 = n1; w2 = n2; w3 = n3;
        }
        const float bb = l1_b[f];
#pragma unroll
        for (int r = 0; r < 8; ++r) H[r * 256 + f] = relu(acc[r] + bb);
    }
    __syncthreads();

    // ---- phase 4: t2 = H @ l2_w (K-split, partials in A/Bt); C += t2 -----
    {
        const int c = tid & 127, kh = tid >> 7;
        float acc[8];
#pragma unroll
        for (int r = 0; r < 8; ++r) acc[r] = 0.f;
        const float* wp = l2_w + kh * 128 * 128 + c;
        float w0 = wp[0 * 128], w1 = wp[1 * 128], w2 = wp[2 * 128], w3 = wp[3 * 128];
        for (int k4 = 0; k4 < 32; ++k4) {
            const int kn = ((k4 + 1) & 31) * 4;
            float n0 = wp[(kn + 0) * 128], n1 = wp[(kn + 1) * 128];
            float n2 = wp[(kn + 2) * 128], n3 = wp[(kn + 3) * 128];
#pragma unroll
            for (int r = 0; r < 8; ++r) {
                float4 t = *(const float4*)(&H[r * 256 + kh * 128 + k4 * 4]);
                acc[r] += t.x * w0 + t.y * w1 + t.z * w2 + t.w * w3;
            }
            w0 = n0; w1 = n1; w2 = n2; w3 = n3;
        }
        float* P = kh ? Bt : A;
#pragma unroll
        for (int r = 0; r < 8; ++r) P[r * 128 + c] = acc[r];
    }
    __syncthreads();
    for (int i = tid; i < 1024; i += 256) {
        int c = i & 127;
        C[i] += l2_b[c] + A[i] + Bt[i];
    }
    __syncthreads();
    ln_rows8(C, n3_g, n3_b, tid);   // C = final tgt
    __syncthreads();

    // ---- phase 5: fused = [F, C] @ fu_w + fu_b; BN partials --------------
    {
        const int c = tid & 63, rg = tid >> 6;
        float acc[2];
        const float fb = fu_b[c];
#pragma unroll
        for (int r = 0; r < 2; ++r) acc[r] = fb;
        const float* wA = fu_w + c;               // rows 0..63 (features half)
        float w0 = wA[0 * 64], w1 = wA[1 * 64], w2 = wA[2 * 64], w3 = wA[3 * 64];
        for (int j4 = 0; j4 < 16; ++j4) {
            const int jn = ((j4 + 1) & 15) * 4;
            float n0 = wA[(jn + 0) * 64], n1 = wA[(jn + 1) * 64];
            float n2 = wA[(jn + 2) * 64], n3 = wA[(jn + 3) * 64];
#pragma unroll
            for (int r = 0; r < 2; ++r) {
                float4 t = *(const float4*)(&F[(rg * 2 + r) * 64 + j4 * 4]);
                acc[r] += t.x * w0 + t.y * w1 + t.z * w2 + t.w * w3;
            }
            w0 = n0; w1 = n1; w2 = n2; w3 = n3;
        }
        const float* wB = fu_w + 64 * 64 + c;     // rows 64..191 (tgt half)
        w0 = wB[0 * 64]; w1 = wB[1 * 64]; w2 = wB[2 * 64]; w3 = wB[3 * 64];
        for (int j4 = 0; j4 < 32; ++j4) {
            const int jn = ((j4 + 1) & 31) * 4;
            float n0 = wB[(jn + 0) * 64], n1 = wB[(jn + 1) * 64];
            float n2 = wB[(jn + 2) * 64], n3 = wB[(jn + 3) * 64];
#pragma unroll
            for (int r = 0; r < 2; ++r) {
                float4 t = *(const float4*)(&C[(rg * 2 + r) * 128 + j4 * 4]);
                acc[r] += t.x * w0 + t.y * w1 + t.z * w2 + t.w * w3;
            }
            w0 = n0; w1 = n1; w2 = n2; w3 = n3;
        }
#pragma unroll
        for (int r = 0; r < 2; ++r) {
            int row = rg * 2 + r;
            float v = acc[r];
            fused[(r0 + row) * 64 + c] = v;
            H[row * 64 + c] = v;
        }
    }
    __syncthreads();
    if (tid < 64) {
        float s = 0.f, s2 = 0.f;
#pragma unroll
        for (int r = 0; r < 8; ++r) { float x = H[r * 64 + tid]; s += x; s2 += x * x; }
        atomicAdd(&bnSum[tid], s);
        atomicAdd(&bnSq[tid], s2);
    }
}

// ---------------------------------------------------------------------------
// K5: batchnorm (train-mode stats) + relu -> fp32 out
// ---------------------------------------------------------------------------
__global__ __launch_bounds__(256) void k5_bn_cst(
    const float* __restrict__ fused, const float* __restrict__ bnSum,
    const float* __restrict__ bnSq,
    const float* __restrict__ g, const float* __restrict__ b,
    float* __restrict__ out, int N)
{
    const int total = N * 64;
    const float invN = 1.f / (float)N;
    for (int i = blockIdx.x * 256 + threadIdx.x; i < total; i += gridDim.x * 256) {
        int c = i & 63;
        float mu = bnSum[c] * invN;
        float var = bnSq[c] * invN - mu * mu;
        float x = fused[i];
        float y = (x - mu) * rsqrtf(var + 1e-3f) * g[c] + b[c];
        out[i] = relu(y);
    }
}

// ---------------------------------------------------------------------------
extern "C" void kernel_launch(void* const* d_in, const int* in_sizes, int n_in,
                              void* d_out, int out_size, void* d_ws, size_t ws_size,
                              hipStream_t stream)
{
    const float* features = (const float*)d_in[0];
    const int*   coords   = (const int*)d_in[1];
    const float* pe_w1 = (const float*)d_in[2];
    const float* pe_b1 = (const float*)d_in[3];
    const float* pe_w2 = (const float*)d_in[4];
    const float* pe_b2 = (const float*)d_in[5];
    const float* in_w  = (const float*)d_in[6];
    const float* in_b  = (const float*)d_in[7];
    const float* q_w   = (const float*)d_in[8];
    const float* q_b   = (const float*)d_in[9];
    const float* k_w   = (const float*)d_in[10];
    const float* k_b   = (const float*)d_in[11];
    const float* v_w   = (const float*)d_in[12];
    const float* v_b   = (const float*)d_in[13];
    const float* o_w   = (const float*)d_in[14];
    const float* o_b   = (const float*)d_in[15];
    const float* n1_g  = (const float*)d_in[16];
    const float* n1_b  = (const float*)d_in[17];
    const float* l1_w  = (const float*)d_in[18];
    const float* l1_b  = (const float*)d_in[19];
    const float* l2_w  = (const float*)d_in[20];
    const float* l2_b  = (const float*)d_in[21];
    const float* n3_g  = (const float*)d_in[22];
    const float* n3_b  = (const float*)d_in[23];
    const float* fu_w  = (const float*)d_in[24];
    const float* fu_b  = (const float*)d_in[25];
    const float* bn_g  = (const float*)d_in[26];
    const float* bn_b  = (const float*)d_in[27];

    const int N = in_sizes[0] / 64;   // 8192

    float* src   = (float*)d_ws;            // N*128
    float* qs    = src + (size_t)N * 128;   // N*128
    float* ks    = qs  + (size_t)N * 128;   // N*128
    float* vs    = ks  + (size_t)N * 128;   // N*128
    float* fused = vs  + (size_t)N * 128;   // N*64
    int*   nbr    = (int*)(fused + (size_t)N * 64);   // N*16 ints
    float* bnSum  = (float*)(nbr + (size_t)N * 16);   // 64
    float* bnSq   = bnSum + 64;                       // 64 (contiguous 128)

    ka_pre_cst<<<N / 8 + N / 16, 256, 0, stream>>>(features, coords,
                                                   pe_w1, pe_b1, pe_w2, pe_b2,
                                                   in_w, in_b, q_w, k_w, v_w,
                                                   src, qs, ks, vs, nbr, bnSum, N);
    k4_main_cst<<<N / 8, 256, 0, stream>>>(features, src, qs, ks, vs, nbr,
                                           q_b, k_b, v_b, o_w, o_b, n1_g, n1_b,
                                           l1_w, l1_b, l2_w, l2_b, n3_g, n3_b,
                                           fu_w, fu_b, fused, bnSum, bnSq);
    k5_bn_cst<<<512, 256, 0, stream>>>(fused, bnSum, bnSq, bn_g, bn_b,
                                       (float*)d_out, N);
}